// Round 8
// baseline (143.423 us; speedup 1.0000x reference)
//
#include <hip/hip_runtime.h>
#include <math.h>

#define E_DIM 8
#define S_DIM 4096
#define B_DIM 8
#define NROWS (B_DIM * S_DIM)          // 32768
#define TCH 512                        // t-chunk staged in LDS
#define TSPLIT 4                       // t-splits (chunks per block = 1024/TCH = 2)
#define NGROUP (NROWS / 128)           // 256 row-groups
#define VSTRIDE 520                    // V^T LDS row stride in halves (16B-aligned)

// 0.5 (attention scale 1/sqrt(E/NH)=0.5) * log2(e), folded into Q before f16
// rounding so scores come out of the QK mfma ready for raw exp2.
#define QSCALE 0.72134752044448170f

typedef __attribute__((ext_vector_type(4))) float f4;
typedef __attribute__((ext_vector_type(4))) __fp16 h4;
typedef __attribute__((ext_vector_type(8))) __fp16 h8;

union QU { uint2 u; h4 h; };

__device__ inline float fast_exp2(float x) {
#if __has_builtin(__builtin_amdgcn_exp2f)
    return __builtin_amdgcn_exp2f(x);
#else
    return exp2f(x);
#endif
}

// Kernel 1: Qh[row] = f16(cos(x@Wq.T+bq+theta)*QSCALE)  (16 B/row);
// Kg[row]  = f16 k[0..7]                                 (16 B/row);
// VTg[batch][e][t] = f16 v  (global V-transpose -> attn staging is vector copies).
// Block 0 also zeroes the split-K counters (ws is re-poisoned before every call).
__global__ __launch_bounds__(256) void qkv_kernel(
    const float* __restrict__ x,
    const float* __restrict__ Wq, const float* __restrict__ bq,
    const float* __restrict__ Wk, const float* __restrict__ bk,
    const float* __restrict__ Wv, const float* __restrict__ bv,
    const float* __restrict__ theta,
    uint4* __restrict__ Qh, uint4* __restrict__ Kg, __fp16* __restrict__ VTg,
    uint* __restrict__ cnt)
{
    if (blockIdx.x == 0 && threadIdx.x < NGROUP) cnt[threadIdx.x] = 0;

    int row = blockIdx.x * blockDim.x + threadIdx.x;
    const float4* x4 = (const float4*)(x + (size_t)row * E_DIM);
    float4 xa = x4[0], xb = x4[1];
    float xr[8] = {xa.x, xa.y, xa.z, xa.w, xb.x, xb.y, xb.z, xb.w};

    float q[8], k[8], v[8];
#pragma unroll
    for (int i = 0; i < 8; ++i) {
        float hq = bq[i], hk = bk[i], hv = bv[i];
#pragma unroll
        for (int j = 0; j < 8; ++j) {
            hq += xr[j] * Wq[i * 8 + j];
            hk += xr[j] * Wk[i * 8 + j];
            hv += xr[j] * Wv[i * 8 + j];
        }
        float th = theta[i];
        q[i] = __cosf(hq + th) * QSCALE;
        k[i] = __cosf(hk + th);
        v[i] = __cosf(hv + th);
    }

    union { uint4 u; __fp16 s[8]; } qp, kp;
#pragma unroll
    for (int i = 0; i < 8; ++i) { qp.s[i] = (__fp16)q[i]; kp.s[i] = (__fp16)k[i]; }
    Qh[row] = qp.u;
    Kg[row] = kp.u;

    int batch = row >> 12;
    int t = row & 4095;
#pragma unroll
    for (int e = 0; e < 8; ++e)     // coalesced across lanes (t contiguous)
        VTg[((size_t)(batch * 8 + e) << 12) + t] = (__fp16)v[e];
}

// Kernel 2: full-MFMA flash attention, 32 rows/wave (2 Q-tiles share every
// K/V fragment read), t-split partials (additively combinable: scores bounded,
// no online rescale needed). One ds_read_b128 of V^T feeds two mfma steps.
// V^T LDS row 8 = ones -> accumulator col 8 = denominator.
// Split-K epilogue: last block per row-group (device-scope atomic counter)
// combines partials, normalizes, applies Wc projection, stores out.
// grid = (NGROUP, TSPLIT), block = 256 (4 waves x 32 rows).
__global__ __launch_bounds__(256) void attn_mfma(
    const uint4* __restrict__ Qh, const uint4* __restrict__ Kg,
    const __fp16* __restrict__ VTg,
    float* __restrict__ ACC, float* __restrict__ DEN,
    uint* __restrict__ cnt,
    const float* __restrict__ Wc, const float* __restrict__ bc,
    float* __restrict__ out)
{
    __shared__ __align__(16) __fp16 Kpad[TCH * 16];      // 16 KB; e=8..15 zero
    __shared__ __align__(16) __fp16 Vt[16 * VSTRIDE];    // 16.25 KB; row8=1, rows9-15=0
    __shared__ int lastFlag;

    int tid = threadIdx.x;
    int l = tid & 63;
    int wv = tid >> 6;
    int rb = blockIdx.x;               // row-group 0..NGROUP-1
    int sp = blockIdx.y;               // t-split 0..3
    int batch = rb >> 5;
    int rbase = rb * 128 + wv * 32;    // wave's 32 global rows

    // one-time constant LDS init (never overwritten by staging):
    for (int r = tid; r < TCH; r += 256)                       // K rows e=8..15 = 0
        *((uint4*)(Kpad + r * 16 + 8)) = make_uint4(0, 0, 0, 0);
    {
        uint* z = (uint*)(Vt + 9 * VSTRIDE);                   // Vt rows 9..15 = 0
        for (int i = tid; i < 7 * VSTRIDE / 2; i += 256) z[i] = 0;
        uint* o1 = (uint*)(Vt + 8 * VSTRIDE);                  // Vt row 8 = 1.0
        for (int i = tid; i < VSTRIDE / 2; i += 256) o1[i] = 0x3C003C00u;
    }

    // Q fragments (loop-invariant): B[k=e][n=r]; lanes 32..63 give e>=8 -> 0
    QU q0u, q1u; q0u.u = make_uint2(0, 0); q1u.u = make_uint2(0, 0);
    if ((l >> 4) < 2) {
        const uint2* Q2 = (const uint2*)Qh;
        q0u.u = Q2[(size_t)(rbase + (l & 15)) * 2 + (l >> 4)];
        q1u.u = Q2[(size_t)(rbase + 16 + (l & 15)) * 2 + (l >> 4)];
    }
    h4 qf0 = q0u.h, qf1 = q1u.h;

    // per-lane fragment address constants
    int koff = ((l & 12) << 1) + (l & 3);            // 8*((l&15)>>2) + (l&3)
    int voff = (l & 15) * VSTRIDE + ((l >> 4) << 3); // halves

    f4 C0 = {0.f, 0.f, 0.f, 0.f};
    f4 C1 = {0.f, 0.f, 0.f, 0.f};

    for (int ch = 0; ch < 1024 / TCH; ++ch) {
        int tb = sp * 1024 + ch * TCH;               // chunk base t within batch
        __syncthreads();                             // covers init / prev compute
        {
            const uint4* src = Kg + ((size_t)batch << 12) + tb;
            for (int i = tid; i < TCH; i += 256)
                *((uint4*)(Kpad + i * 16)) = src[i];
        }
        {
            for (int i = tid; i < 8 * (TCH / 8); i += 256) {   // 512 uint4
                int e = i >> 6, c = i & 63;
                const uint4* src = (const uint4*)(VTg + (((size_t)(batch * 8 + e)) << 12) + tb);
                *((uint4*)(Vt + e * VSTRIDE + c * 8)) = src[c];
            }
        }
        __syncthreads();

#pragma unroll 4
        for (int ds = 0; ds < TCH / 32; ++ds) {      // 16 double-steps of 32 t
            int krow = ds * 32 + koff;
            h4 kf0 = *((const h4*)(Kpad + (krow << 4) + ((l >> 4) << 2)));
            h4 kf1 = *((const h4*)(Kpad + ((krow + 4) << 4) + ((l >> 4) << 2)));
            h8 vr = *((const h8*)(Vt + voff + ds * 32));
            h4 vlo = __builtin_shufflevector(vr, vr, 0, 1, 2, 3);
            h4 vhi = __builtin_shufflevector(vr, vr, 4, 5, 6, 7);

            f4 z = {0.f, 0.f, 0.f, 0.f};
            f4 s00 = __builtin_amdgcn_mfma_f32_16x16x16f16(kf0, qf0, z, 0, 0, 0);
            f4 s01 = __builtin_amdgcn_mfma_f32_16x16x16f16(kf1, qf0, z, 0, 0, 0);
            f4 s10 = __builtin_amdgcn_mfma_f32_16x16x16f16(kf0, qf1, z, 0, 0, 0);
            f4 s11 = __builtin_amdgcn_mfma_f32_16x16x16f16(kf1, qf1, z, 0, 0, 0);

            h4 p00, p01, p10, p11;
#pragma unroll
            for (int i = 0; i < 4; ++i) {
                p00[i] = (__fp16)fast_exp2(s00[i]);
                p01[i] = (__fp16)fast_exp2(s01[i]);
                p10[i] = (__fp16)fast_exp2(s10[i]);
                p11[i] = (__fp16)fast_exp2(s11[i]);
            }
            C0 = __builtin_amdgcn_mfma_f32_16x16x16f16(p00, vlo, C0, 0, 0, 0);
            C0 = __builtin_amdgcn_mfma_f32_16x16x16f16(p01, vhi, C0, 0, 0, 0);
            C1 = __builtin_amdgcn_mfma_f32_16x16x16f16(p10, vlo, C1, 0, 0, 0);
            C1 = __builtin_amdgcn_mfma_f32_16x16x16f16(p11, vhi, C1, 0, 0, 0);
        }
    }

    // Write partials. C: lane l reg i = Onum[row 4*(l>>4)+i][e=l&15]; col8=den.
    int e = l & 15;
    int g = l >> 4;
#pragma unroll
    for (int i = 0; i < 4; ++i) {
        int r0 = rbase + 4 * g + i;
        if (e < 8) {
            ACC[(((size_t)sp * NROWS + r0) << 3) + e] = C0[i];
            ACC[(((size_t)sp * NROWS + r0 + 16) << 3) + e] = C1[i];
        } else if (e == 8) {
            DEN[(size_t)sp * NROWS + r0] = C0[i];
            DEN[(size_t)sp * NROWS + r0 + 16] = C1[i];
        }
    }

    // Split-K last-block-wins epilogue (G16: release via device fence ->
    // buffer_wbl2 pushes this XCD's L2 to the coherent point; acquire via
    // device fence -> buffer_inv before reading other blocks' partials).
    __syncthreads();                   // drains all threads' stores (vmcnt(0))
    if (tid == 0) {
        __threadfence();               // device-scope release
        uint old = atomicAdd(&cnt[rb], 1u);
        lastFlag = (old == TSPLIT - 1) ? 1 : 0;
    }
    __syncthreads();
    if (!lastFlag) return;
    __threadfence();                   // device-scope acquire

    if (tid < 128) {
        int row = rb * 128 + tid;
        float a[8] = {0,0,0,0,0,0,0,0};
        float den = 0.f;
#pragma unroll
        for (int s = 0; s < TSPLIT; ++s) {
            const float4* A4 = (const float4*)(ACC + (((size_t)s * NROWS + row) << 3));
            float4 p0 = A4[0], p1 = A4[1];
            a[0] += p0.x; a[1] += p0.y; a[2] += p0.z; a[3] += p0.w;
            a[4] += p1.x; a[5] += p1.y; a[6] += p1.z; a[7] += p1.w;
            den += DEN[(size_t)s * NROWS + row];
        }
        float inv = 1.0f / den;
#pragma unroll
        for (int j = 0; j < 8; ++j) a[j] *= inv;
        float r[8];
#pragma unroll
        for (int i = 0; i < 8; ++i) {
            float h = bc[i];
#pragma unroll
            for (int j = 0; j < 8; ++j) h += a[j] * Wc[i * 8 + j];
            r[i] = h;
        }
        float4* O4 = (float4*)(out + (size_t)row * 8);
        O4[0] = make_float4(r[0], r[1], r[2], r[3]);
        O4[1] = make_float4(r[4], r[5], r[6], r[7]);
    }
}

extern "C" void kernel_launch(void* const* d_in, const int* in_sizes, int n_in,
                              void* d_out, int out_size, void* d_ws, size_t ws_size,
                              hipStream_t stream) {
    const float* x     = (const float*)d_in[0];
    const float* Wq    = (const float*)d_in[1];
    const float* bq    = (const float*)d_in[2];
    const float* Wk    = (const float*)d_in[3];
    const float* bk    = (const float*)d_in[4];
    const float* Wv    = (const float*)d_in[5];
    const float* bv    = (const float*)d_in[6];
    const float* theta = (const float*)d_in[7];
    const float* Wc    = (const float*)d_in[8];
    const float* bc    = (const float*)d_in[9];
    float* out = (float*)d_out;

    // ws (f32 units): Qh 4/row, Kg 4/row, VTg 4/row, ACC TSPLIT*8/row,
    // DEN TSPLIT/row, then NGROUP counters.
    float* ws  = (float*)d_ws;
    uint4*  Qh  = (uint4*)ws;
    uint4*  Kg  = (uint4*)(ws + (size_t)NROWS * 4);
    __fp16* VTg = (__fp16*)(ws + (size_t)NROWS * 8);
    float*  ACC = ws + (size_t)NROWS * 12;
    float*  DEN = ACC + (size_t)TSPLIT * NROWS * 8;
    uint*   cnt = (uint*)(DEN + (size_t)TSPLIT * NROWS);
    // total ~6.3 MB << ws_size

    qkv_kernel<<<NROWS / 256, 256, 0, stream>>>(x, Wq, bq, Wk, bk, Wv, bv, theta,
                                                Qh, Kg, VTg, cnt);

    dim3 grid2(NGROUP, TSPLIT);        // (256, 4)
    attn_mfma<<<grid2, 256, 0, stream>>>(Qh, Kg, VTg, ACC, DEN, cnt, Wc, bc, out);
}

// Round 9
// 101.186 us; speedup vs baseline: 1.4174x; 1.4174x over previous
//
#include <hip/hip_runtime.h>
#include <math.h>

#define E_DIM 8
#define S_DIM 4096
#define B_DIM 8
#define NROWS (B_DIM * S_DIM)          // 32768
#define TCH 512                        // t-chunk staged in LDS
#define TSPLIT 4                       // t-splits (chunks per block = 1024/TCH = 2)
#define KSTRIDE 9                      // K LDS row stride in DWORDS (36 B: bank-spreads h)
#define VSTRIDE 520                    // V^T LDS row stride in halves (16B-aligned)

// 0.5 (attention scale 1/sqrt(E/NH)=0.5) * log2(e), folded into Q before f16
// rounding so scores come out of the QK mfma ready for raw exp2.
#define QSCALE 0.72134752044448170f

typedef __attribute__((ext_vector_type(4))) float f4;
typedef __attribute__((ext_vector_type(4))) __fp16 h4;
typedef __attribute__((ext_vector_type(8))) __fp16 h8;

union QU { uint2 u; h4 h; };
union U2H { uint u[2]; h4 h; };

__device__ inline float fast_exp2(float x) {
#if __has_builtin(__builtin_amdgcn_exp2f)
    return __builtin_amdgcn_exp2f(x);
#else
    return exp2f(x);
#endif
}

// Kernel 1: Qh[row] = f16(cos(x@Wq.T+bq+theta)*QSCALE)  (16 B/row);
// Kg[row]  = f16 k[0..7]                                 (16 B/row);
// VTg[batch][e][t] = f16 v  (global V-transpose -> attn staging is vector copies).
__global__ __launch_bounds__(256) void qkv_kernel(
    const float* __restrict__ x,
    const float* __restrict__ Wq, const float* __restrict__ bq,
    const float* __restrict__ Wk, const float* __restrict__ bk,
    const float* __restrict__ Wv, const float* __restrict__ bv,
    const float* __restrict__ theta,
    uint4* __restrict__ Qh, uint4* __restrict__ Kg, __fp16* __restrict__ VTg)
{
    int row = blockIdx.x * blockDim.x + threadIdx.x;
    const float4* x4 = (const float4*)(x + (size_t)row * E_DIM);
    float4 xa = x4[0], xb = x4[1];
    float xr[8] = {xa.x, xa.y, xa.z, xa.w, xb.x, xb.y, xb.z, xb.w};

    float q[8], k[8], v[8];
#pragma unroll
    for (int i = 0; i < 8; ++i) {
        float hq = bq[i], hk = bk[i], hv = bv[i];
#pragma unroll
        for (int j = 0; j < 8; ++j) {
            hq += xr[j] * Wq[i * 8 + j];
            hk += xr[j] * Wk[i * 8 + j];
            hv += xr[j] * Wv[i * 8 + j];
        }
        float th = theta[i];
        q[i] = __cosf(hq + th) * QSCALE;
        k[i] = __cosf(hk + th);
        v[i] = __cosf(hv + th);
    }

    union { uint4 u; __fp16 s[8]; } qp, kp;
#pragma unroll
    for (int i = 0; i < 8; ++i) { qp.s[i] = (__fp16)q[i]; kp.s[i] = (__fp16)k[i]; }
    Qh[row] = qp.u;
    Kg[row] = kp.u;

    int batch = row >> 12;
    int t = row & 4095;
#pragma unroll
    for (int e = 0; e < 8; ++e)     // coalesced across lanes (t contiguous)
        VTg[((size_t)(batch * 8 + e) << 12) + t] = (__fp16)v[e];
}

// Kernel 2: full-MFMA flash attention, 32 rows/wave (2 Q-tiles share every
// K/V fragment read), t-split partials (additively combinable: scores bounded,
// no online rescale needed). One ds_read_b128 of V^T feeds two mfma steps.
// V^T LDS row 8 = ones -> accumulator col 8 = denominator.
// K staged at 9-dword row stride: bank = 8h+9q+2*half mod 32 -> exactly
// 2 lanes/bank (uniform) -> conflict-free fragment reads (was 4-way at 32 B).
// grid = (NROWS/128, TSPLIT), block = 256 (4 waves x 32 rows).
__global__ __launch_bounds__(256) void attn_mfma(
    const uint4* __restrict__ Qh, const uint4* __restrict__ Kg,
    const __fp16* __restrict__ VTg,
    float* __restrict__ ACC, float* __restrict__ DEN)
{
    __shared__ uint KpadW[TCH * KSTRIDE];                // 18 KB; dwords 4-7/row = 0
    __shared__ __align__(16) __fp16 Vt[16 * VSTRIDE];    // 16.25 KB; row8=1, rows9-15=0

    int tid = threadIdx.x;
    int l = tid & 63;
    int wv = tid >> 6;
    int rb = blockIdx.x;               // row-group 0..255
    int sp = blockIdx.y;               // t-split 0..3
    int batch = rb >> 5;
    int rbase = rb * 128 + wv * 32;    // wave's 32 global rows

    // one-time constant LDS init (Vt rows 8..15; staging only writes rows 0..7)
    {
        uint* z = (uint*)(Vt + 9 * VSTRIDE);                   // Vt rows 9..15 = 0
        for (int i = tid; i < 7 * VSTRIDE / 2; i += 256) z[i] = 0;
        uint* o1 = (uint*)(Vt + 8 * VSTRIDE);                  // Vt row 8 = 1.0
        for (int i = tid; i < VSTRIDE / 2; i += 256) o1[i] = 0x3C003C00u;
    }

    // Q fragments (loop-invariant): B[k=e][n=r]; lanes 32..63 give e>=8 -> 0
    QU q0u, q1u; q0u.u = make_uint2(0, 0); q1u.u = make_uint2(0, 0);
    if ((l >> 4) < 2) {
        const uint2* Q2 = (const uint2*)Qh;
        q0u.u = Q2[(size_t)(rbase + (l & 15)) * 2 + (l >> 4)];
        q1u.u = Q2[(size_t)(rbase + 16 + (l & 15)) * 2 + (l >> 4)];
    }
    h4 qf0 = q0u.h, qf1 = q1u.h;

    // per-lane fragment address constants
    int koff = ((l & 12) << 1) + (l & 3);            // 8*((l&15)>>2) + (l&3)
    int half = l >> 4;
    int kdw = koff * KSTRIDE + 2 * half;             // dword offset within K tile
    int voff = (l & 15) * VSTRIDE + (half << 3);     // halves

    f4 C0 = {0.f, 0.f, 0.f, 0.f};
    f4 C1 = {0.f, 0.f, 0.f, 0.f};

    for (int ch = 0; ch < 1024 / TCH; ++ch) {
        int tb = sp * 1024 + ch * TCH;               // chunk base t within batch
        __syncthreads();                             // covers init / prev compute
        // stage K: 512 rows; dwords 0-3 = k data, 4-7 = zero (e>=8), 8 = pad
        {
            const uint4* src = Kg + ((size_t)batch << 12) + tb;
            for (int i = tid; i < TCH; i += 256) {
                uint4 kk = src[i];
                uint* dst = KpadW + i * KSTRIDE;
                dst[0] = kk.x; dst[1] = kk.y; dst[2] = kk.z; dst[3] = kk.w;
                dst[4] = 0; dst[5] = 0; dst[6] = 0; dst[7] = 0;
            }
        }
        // stage V^T: 8 rows x 512 halves (vector copies, no scatter)
        {
            for (int i = tid; i < 8 * (TCH / 8); i += 256) {   // 512 uint4
                int e = i >> 6, c = i & 63;
                const uint4* src = (const uint4*)(VTg + (((size_t)(batch * 8 + e)) << 12) + tb);
                *((uint4*)(Vt + e * VSTRIDE + c * 8)) = src[c];
            }
        }
        __syncthreads();

#pragma unroll 4
        for (int ds = 0; ds < TCH / 32; ++ds) {      // 16 double-steps of 32 t
            int b0 = ds * 32 * KSTRIDE + kdw;
            U2H k0u, k1u;
            k0u.u[0] = KpadW[b0];
            k0u.u[1] = KpadW[b0 + 1];
            k1u.u[0] = KpadW[b0 + 4 * KSTRIDE];
            k1u.u[1] = KpadW[b0 + 4 * KSTRIDE + 1];
            h4 kf0 = k0u.h, kf1 = k1u.h;
            h8 vr = *((const h8*)(Vt + voff + ds * 32));
            h4 vlo = __builtin_shufflevector(vr, vr, 0, 1, 2, 3);
            h4 vhi = __builtin_shufflevector(vr, vr, 4, 5, 6, 7);

            f4 z = {0.f, 0.f, 0.f, 0.f};
            f4 s00 = __builtin_amdgcn_mfma_f32_16x16x16f16(kf0, qf0, z, 0, 0, 0);
            f4 s01 = __builtin_amdgcn_mfma_f32_16x16x16f16(kf1, qf0, z, 0, 0, 0);
            f4 s10 = __builtin_amdgcn_mfma_f32_16x16x16f16(kf0, qf1, z, 0, 0, 0);
            f4 s11 = __builtin_amdgcn_mfma_f32_16x16x16f16(kf1, qf1, z, 0, 0, 0);

            h4 p00, p01, p10, p11;
#pragma unroll
            for (int i = 0; i < 4; ++i) {
                p00[i] = (__fp16)fast_exp2(s00[i]);
                p01[i] = (__fp16)fast_exp2(s01[i]);
                p10[i] = (__fp16)fast_exp2(s10[i]);
                p11[i] = (__fp16)fast_exp2(s11[i]);
            }
            C0 = __builtin_amdgcn_mfma_f32_16x16x16f16(p00, vlo, C0, 0, 0, 0);
            C0 = __builtin_amdgcn_mfma_f32_16x16x16f16(p01, vhi, C0, 0, 0, 0);
            C1 = __builtin_amdgcn_mfma_f32_16x16x16f16(p10, vlo, C1, 0, 0, 0);
            C1 = __builtin_amdgcn_mfma_f32_16x16x16f16(p11, vhi, C1, 0, 0, 0);
        }
    }

    // C: lane l reg i = Onum[row 4*(l>>4)+i][e=l&15]; col 8 = denominator.
    int e = l & 15;
    int g = l >> 4;
#pragma unroll
    for (int i = 0; i < 4; ++i) {
        int r0 = rbase + 4 * g + i;
        if (e < 8) {
            ACC[(((size_t)sp * NROWS + r0) << 3) + e] = C0[i];
            ACC[(((size_t)sp * NROWS + r0 + 16) << 3) + e] = C1[i];
        } else if (e == 8) {
            DEN[(size_t)sp * NROWS + r0] = C0[i];
            DEN[(size_t)sp * NROWS + r0 + 16] = C1[i];
        }
    }
}

// Kernel 3: combine t-split partials, normalize, fused Wc projection.
__global__ __launch_bounds__(256) void finalize_kernel(
    const float* __restrict__ ACC, const float* __restrict__ DEN,
    const float* __restrict__ Wc, const float* __restrict__ bc,
    float* __restrict__ out)
{
    int row = blockIdx.x * blockDim.x + threadIdx.x;
    float a[8] = {0,0,0,0,0,0,0,0};
    float den = 0.f;
#pragma unroll
    for (int sp = 0; sp < TSPLIT; ++sp) {
        const float4* A4 = (const float4*)(ACC + (((size_t)sp * NROWS + row) << 3));
        float4 p0 = A4[0], p1 = A4[1];
        a[0] += p0.x; a[1] += p0.y; a[2] += p0.z; a[3] += p0.w;
        a[4] += p1.x; a[5] += p1.y; a[6] += p1.z; a[7] += p1.w;
        den += DEN[(size_t)sp * NROWS + row];
    }
    float inv = 1.0f / den;
#pragma unroll
    for (int j = 0; j < 8; ++j) a[j] *= inv;
    float r[8];
#pragma unroll
    for (int i = 0; i < 8; ++i) {
        float h = bc[i];
#pragma unroll
        for (int j = 0; j < 8; ++j) h += a[j] * Wc[i * 8 + j];
        r[i] = h;
    }
    float4* O4 = (float4*)(out + (size_t)row * 8);
    O4[0] = make_float4(r[0], r[1], r[2], r[3]);
    O4[1] = make_float4(r[4], r[5], r[6], r[7]);
}

extern "C" void kernel_launch(void* const* d_in, const int* in_sizes, int n_in,
                              void* d_out, int out_size, void* d_ws, size_t ws_size,
                              hipStream_t stream) {
    const float* x     = (const float*)d_in[0];
    const float* Wq    = (const float*)d_in[1];
    const float* bq    = (const float*)d_in[2];
    const float* Wk    = (const float*)d_in[3];
    const float* bk    = (const float*)d_in[4];
    const float* Wv    = (const float*)d_in[5];
    const float* bv    = (const float*)d_in[6];
    const float* theta = (const float*)d_in[7];
    const float* Wc    = (const float*)d_in[8];
    const float* bc    = (const float*)d_in[9];
    float* out = (float*)d_out;

    // ws (f32 units): Qh 4/row, Kg 4/row, VTg 4/row, ACC TSPLIT*8/row, DEN TSPLIT/row
    float* ws  = (float*)d_ws;
    uint4*  Qh  = (uint4*)ws;
    uint4*  Kg  = (uint4*)(ws + (size_t)NROWS * 4);
    __fp16* VTg = (__fp16*)(ws + (size_t)NROWS * 8);
    float*  ACC = ws + (size_t)NROWS * 12;
    float*  DEN = ACC + (size_t)TSPLIT * NROWS * 8;
    // total ~6.3 MB << ws_size

    qkv_kernel<<<NROWS / 256, 256, 0, stream>>>(x, Wq, bq, Wk, bk, Wv, bv, theta, Qh, Kg, VTg);

    dim3 grid2(NROWS / 128, TSPLIT);   // (256, 4)
    attn_mfma<<<grid2, 256, 0, stream>>>(Qh, Kg, VTg, ACC, DEN);

    finalize_kernel<<<NROWS / 256, 256, 0, stream>>>(ACC, DEN, Wc, bc, out);
}